// Round 4
// baseline (35.991 us; speedup 1.0000x reference)
//
#include <hip/hip_runtime.h>

// Single fused kernel. 1024 threads/block (16 waves), one wave64 = 2 batches
// (lanes 0-31 / 32-63). Unordered pairs via rotation t=1..16 (t=16 weight 0.5).
// Rank (5 bits, 0=invalid) packed into score mantissa LSBs -> 1 shuffle/pair.
// Block partials -> ws; last block (atomic ticket) reduces all partials inline.
// Ticket is zeroed each call by a 4-byte hipMemsetAsync node.
__global__ __launch_bounds__(1024) void ranknet_fused_kernel(
    const float* __restrict__ scores,
    const int*   __restrict__ rankings,
    const int*   __restrict__ mask,
    unsigned*    __restrict__ counter,
    float2*      __restrict__ partials,
    int nblocks,
    float*       __restrict__ out)
{
    const int tid  = blockIdx.x * 1024 + threadIdx.x;
    const int lane = threadIdx.x & 63;
    const int wave = threadIdx.x >> 6;

    const float s = scores[tid];
    const int   r = rankings[tid];
    const int   m = mask[tid];
    const int   rr = (m != 0 && r > 0) ? r : 0;          // 0 encodes invalid

    const unsigned su = (__float_as_uint(s) & ~31u) | (unsigned)rr;
    const float sj = __uint_as_float(su);
    const int   rj = rr;

    const int item = lane & 31;
    const int half = lane & 32;

    // all shuffles up front, pinned in registers
    unsigned pk[16];
    #pragma unroll
    for (int t = 1; t <= 16; ++t)
        pk[t - 1] = __shfl(su, half | ((item + t) & 31));

    float lsum = 0.0f;
    float lcnt = 0.0f;
    #pragma unroll
    for (int t = 1; t <= 16; ++t) {
        const unsigned pu = pk[t - 1];
        const int   ri = (int)(pu & 31u);
        const float si = __uint_as_float(pu);

        const float x  = si - sj;                        // s_i - s_j
        const float y  = (ri < rj) ? -x : x;             // loss = softplus(y)
        const float e  = __expf(-fabsf(y));
        const float sp = fmaxf(y, 0.0f) + __logf(1.0f + e);

        const bool valid = (ri != 0) & (rj != 0) & (ri != rj);
        const float w  = (t == 16) ? 0.5f : 1.0f;
        const float ws = valid ? w : 0.0f;
        lsum = fmaf(ws, sp, lsum);
        lcnt += ws;
    }

    // per-batch butterfly within each 32-lane half
    #pragma unroll
    for (int off = 16; off > 0; off >>= 1) {
        lsum += __shfl_xor(lsum, off);
        lcnt += __shfl_xor(lcnt, off);
    }
    float pb  = (lcnt > 0.0f) ? (lsum / lcnt) : 0.0f;    // per-batch mean
    float has = (lcnt > 0.0f) ? 1.0f : 0.0f;
    pb  += __shfl_xor(pb, 32);                           // combine wave's 2 batches
    has += __shfl_xor(has, 32);

    __shared__ float2 wpart[16];
    __shared__ float2 bpart[16];
    __shared__ int    lastflag;
    if (lane == 0) wpart[wave] = make_float2(pb, has);
    __syncthreads();

    // block-level reduce by wave 0, then ticket
    if (wave == 0) {
        float2 v = (lane < 16) ? wpart[lane] : make_float2(0.0f, 0.0f);
        #pragma unroll
        for (int off = 8; off > 0; off >>= 1) {
            v.x += __shfl_xor(v.x, off);
            v.y += __shfl_xor(v.y, off);
        }
        if (lane == 0) {
            partials[blockIdx.x] = v;
            __threadfence();                             // release partial
            const unsigned old = atomicAdd(counter, 1u);
            lastflag = (old == (unsigned)(nblocks - 1)) ? 1 : 0;
        }
    }
    __syncthreads();
    if (!lastflag) return;

    // last block: reduce all partials (fixed order -> bitwise deterministic)
    __threadfence();                                     // acquire
    float ps = 0.0f, pc = 0.0f;
    for (int i = threadIdx.x; i < nblocks; i += 1024) {
        const float2 p = partials[i];
        ps += p.x;
        pc += p.y;
    }
    #pragma unroll
    for (int off = 32; off > 0; off >>= 1) {
        ps += __shfl_xor(ps, off);
        pc += __shfl_xor(pc, off);
    }
    if (lane == 0) bpart[wave] = make_float2(ps, pc);
    __syncthreads();
    if (threadIdx.x == 0) {
        float ts = 0.0f, tc = 0.0f;
        #pragma unroll
        for (int w = 0; w < 16; ++w) { ts += bpart[w].x; tc += bpart[w].y; }
        out[0] = (tc > 0.0f) ? (ts / tc) : 0.0f;
    }
}

extern "C" void kernel_launch(void* const* d_in, const int* in_sizes, int n_in,
                              void* d_out, int out_size, void* d_ws, size_t ws_size,
                              hipStream_t stream) {
    const float* scores   = (const float*)d_in[0];
    const int*   rankings = (const int*)d_in[1];
    const int*   mask     = (const int*)d_in[2];
    float*       out      = (float*)d_out;

    const int total   = in_sizes[0];          // B * 32 = 1,048,576
    const int nblocks = total / 1024;         // 1024 blocks x 16 waves

    unsigned* counter  = (unsigned*)d_ws;                       // 4 B ticket
    float2*   partials = (float2*)((char*)d_ws + 64);           // 8 KB

    hipMemsetAsync(counter, 0, sizeof(unsigned), stream);       // capturable node
    ranknet_fused_kernel<<<nblocks, 1024, 0, stream>>>(
        scores, rankings, mask, counter, partials, nblocks, out);
}

// Round 6
// 17.227 us; speedup vs baseline: 2.0893x; 2.0893x over previous
//
#include <hip/hip_runtime.h>

// Two-kernel structure (only plain launches survive graph capture here).
// Kernel 1: 1024 blocks x 256 threads; each thread handles 4 item slots.
// One wave64 = 2 batches per set (lanes 0-31 / 32-63), 8 batches per wave total.
// Unordered pairs via rotation t=1..15 (each pair once) + t=16 antipodal pairs
// processed only by lanes with item<16 (each once). 496 = C(32,2) pairs/batch.
// Rank (5 bits, 0=invalid) packed into score mantissa LSBs -> 1 shuffle/pair.
// Trans diet: sum softplus = sum max(y,0) + log(prod(1+e)) -> 16 exp + 1 log
// per 16 pairs (prod <= 2^16, no overflow).
__global__ __launch_bounds__(256) void ranknet_partial_kernel(
    const float* __restrict__ scores,
    const int*   __restrict__ rankings,
    const int*   __restrict__ mask,
    float2*      __restrict__ partials)
{
    const int lane = threadIdx.x & 63;
    const int wave = threadIdx.x >> 6;
    const int item = lane & 31;
    const int half = lane & 32;
    const int base = blockIdx.x * 1024;

    float pb_acc  = 0.0f;   // sum of per-batch mean losses
    float has_acc = 0.0f;   // count of batches with >=1 valid pair

    #pragma unroll
    for (int set = 0; set < 4; ++set) {
        const int idx = base + set * 256 + threadIdx.x;   // coalesced
        const float s = scores[idx];
        const int   r = rankings[idx];
        const int   m = mask[idx];
        const int   rr = (m != 0 && r > 0) ? r : 0;       // 0 encodes invalid

        const unsigned su = (__float_as_uint(s) & ~31u) | (unsigned)rr;
        const float sj = __uint_as_float(su);
        const int   rj = rr;

        // all shuffles up front, pinned in registers
        unsigned pk[16];
        #pragma unroll
        for (int t = 1; t <= 16; ++t)
            pk[t - 1] = __shfl(su, half | ((item + t) & 31));

        float ysum = 0.0f;   // sum of max(y,0) over valid pairs
        float prod = 1.0f;   // product of (1+e^{-|y|}) over valid pairs
        float cnt  = 0.0f;
        #pragma unroll
        for (int t = 1; t <= 16; ++t) {
            const unsigned pu = pk[t - 1];
            const int   ri = (int)(pu & 31u);
            const float si = __uint_as_float(pu);

            const float x = si - sj;                      // s_i - s_j
            const float y = (ri < rj) ? -x : x;           // loss = softplus(y)
            const float e = __expf(-fabsf(y));

            bool valid = (ri != 0) & (rj != 0) & (ri != rj);
            if (t == 16) valid = valid && (item < 16);    // antipodal: count once
            ysum += valid ? fmaxf(y, 0.0f) : 0.0f;
            prod *= valid ? (1.0f + e) : 1.0f;
            cnt  += valid ? 1.0f : 0.0f;
        }
        float lsum = ysum + __logf(prod);                 // one log per 16 pairs
        float lcnt = cnt;

        // butterfly within each 32-lane half (per-batch reduction)
        #pragma unroll
        for (int off = 16; off > 0; off >>= 1) {
            lsum += __shfl_xor(lsum, off);
            lcnt += __shfl_xor(lcnt, off);
        }
        pb_acc  += (lcnt > 0.0f) ? (lsum / lcnt) : 0.0f;
        has_acc += (lcnt > 0.0f) ? 1.0f : 0.0f;
    }

    // combine the wave's two halves, then the block's four waves
    pb_acc  += __shfl_xor(pb_acc, 32);
    has_acc += __shfl_xor(has_acc, 32);

    __shared__ float2 wpart[4];
    if (lane == 0) wpart[wave] = make_float2(pb_acc, has_acc);
    __syncthreads();
    if (threadIdx.x == 0) {
        float ps = 0.0f, pc = 0.0f;
        #pragma unroll
        for (int w2 = 0; w2 < 4; ++w2) { ps += wpart[w2].x; pc += wpart[w2].y; }
        partials[blockIdx.x] = make_float2(ps, pc);
    }
}

__global__ __launch_bounds__(256) void ranknet_finalize_kernel(
    const float2* __restrict__ partials, int n, float* __restrict__ out)
{
    float s = 0.0f, c = 0.0f;
    for (int i = threadIdx.x; i < n; i += 256) {
        const float2 p = partials[i];
        s += p.x;
        c += p.y;
    }
    #pragma unroll
    for (int off = 32; off > 0; off >>= 1) {
        s += __shfl_xor(s, off);
        c += __shfl_xor(c, off);
    }
    __shared__ float2 wsum[4];
    const int wave = threadIdx.x >> 6;
    const int lane = threadIdx.x & 63;
    if (lane == 0) wsum[wave] = make_float2(s, c);
    __syncthreads();
    if (threadIdx.x == 0) {
        float ts = 0.0f, tc = 0.0f;
        #pragma unroll
        for (int w = 0; w < 4; ++w) { ts += wsum[w].x; tc += wsum[w].y; }
        out[0] = (tc > 0.0f) ? (ts / tc) : 0.0f;
    }
}

extern "C" void kernel_launch(void* const* d_in, const int* in_sizes, int n_in,
                              void* d_out, int out_size, void* d_ws, size_t ws_size,
                              hipStream_t stream) {
    const float* scores   = (const float*)d_in[0];
    const int*   rankings = (const int*)d_in[1];
    const int*   mask     = (const int*)d_in[2];
    float*       out      = (float*)d_out;

    const int total   = in_sizes[0];        // B * 32 = 1,048,576
    const int nblocks = total / 1024;       // 1024 blocks, 32 batches per block

    float2* partials = (float2*)d_ws;       // 1024 * 8B = 8 KB, every slot written

    ranknet_partial_kernel<<<nblocks, 256, 0, stream>>>(scores, rankings, mask, partials);
    ranknet_finalize_kernel<<<1, 256, 0, stream>>>(partials, nblocks, out);
}

// Round 7
// 15.864 us; speedup vs baseline: 2.2688x; 1.0859x over previous
//
#include <hip/hip_runtime.h>

// Kernel 1: 1024 blocks x 256 threads. Each thread loads 4 CONSECUTIVE items
// via float4/int4 (perfectly coalesced). An 8-lane group holds one 32-item
// batch (lane q8=lane&7 holds local items 4*q8..4*q8+3); a wave64 covers 8
// batches. Unordered pairs via rotation t=1..15 (each pair once) + t=16 for
// local item < 16 (antipodal pairs once): 496 = C(32,2).
// Partner of item 4*q8+c under rotation t: group-lane (q8+((c+t)>>2))&7,
// component (c+t)&3 -> compile-time constants, 1 shuffle per pair.
// Scores pre-scaled by log2(e): e^{-|y|} = 2^{-|x'|} (exp2 with free -|.|
// modifier); sum softplus = ln2*(sum max(y',0) + log2(prod(1+e))).
// Rank (5 bits, 0=invalid) packed into score mantissa LSBs.
__global__ __launch_bounds__(256) void ranknet_partial_kernel(
    const float4* __restrict__ scores4,
    const int4*   __restrict__ rank4,
    const int4*   __restrict__ mask4,
    float2*       __restrict__ partials)
{
    const int gid  = blockIdx.x * 256 + threadIdx.x;
    const int lane = threadIdx.x & 63;
    const int wave = threadIdx.x >> 6;

    const float4 s4 = scores4[gid];
    const int4   r4 = rank4[gid];
    const int4   m4 = mask4[gid];

    const float L2E = 1.4426950408889634f;

    unsigned su[4];      // packed: scaled score with rank in low 5 mantissa bits
    int      rj[4];
    float    rjnz[4];
    {
        const float sv[4] = {s4.x, s4.y, s4.z, s4.w};
        const int   rv[4] = {r4.x, r4.y, r4.z, r4.w};
        const int   mv[4] = {m4.x, m4.y, m4.z, m4.w};
        #pragma unroll
        for (int c = 0; c < 4; ++c) {
            const int rr = (mv[c] != 0 && rv[c] > 0) ? rv[c] : 0;
            su[c]   = (__float_as_uint(sv[c] * L2E) & ~31u) | (unsigned)rr;
            rj[c]   = rr;
            rjnz[c] = (rr != 0) ? 1.0f : 0.0f;
        }
    }

    float A = 0.0f;   // sum of max(y',0)  (log2 domain)
    float P = 1.0f;   // product of (1 + 2^{-|x'|}), gated; <= 2^64
    float C = 0.0f;   // valid-pair count

    const bool low = ((lane & 7) < 4);    // holds local items < 16 (for t=16)

    #pragma unroll
    for (int t = 1; t <= 16; ++t) {
        #pragma unroll
        for (int c = 0; c < 4; ++c) {
            const int delta = (t + c) >> 2;          // compile-time
            const int gamma = (t + c) & 3;           // compile-time
            const int src   = (lane & ~7) | ((lane + delta) & 7);
            const unsigned pu = __shfl(su[gamma], src);

            const int   ri = (int)(pu & 31u);
            const float x  = __uint_as_float(pu) - __uint_as_float(su[c]);
            const float y  = (ri < rj[c]) ? -x : x;  // loss = softplus(y)/ln2 dom.
            const float e  = __builtin_exp2f(-__builtin_fabsf(x));

            float validf = ((ri != 0) && (ri != rj[c])) ? rjnz[c] : 0.0f;
            if (t == 16) validf = low ? validf : 0.0f;

            A  = fmaf(validf, fmaxf(y, 0.0f), A);
            P *= fmaf(validf, e, 1.0f);
            C += validf;
        }
    }

    // per-lane log, then 3-level butterfly within the 8-lane group (one batch)
    float v = A + __builtin_log2f(P);
    #pragma unroll
    for (int off = 1; off <= 4; off <<= 1) {
        v += __shfl_xor(v, off);
        C += __shfl_xor(C, off);
    }
    float pb  = (C > 0.0f) ? (v * 0.6931471805599453f) / C : 0.0f;
    float has = (C > 0.0f) ? 1.0f : 0.0f;

    // sum per-batch means across the wave's 8 groups (8 batches)
    #pragma unroll
    for (int off = 8; off <= 32; off <<= 1) {
        pb  += __shfl_xor(pb, off);
        has += __shfl_xor(has, off);
    }

    __shared__ float2 wpart[4];
    if (lane == 0) wpart[wave] = make_float2(pb, has);
    __syncthreads();
    if (threadIdx.x == 0) {
        float ps = 0.0f, pc = 0.0f;
        #pragma unroll
        for (int w2 = 0; w2 < 4; ++w2) { ps += wpart[w2].x; pc += wpart[w2].y; }
        partials[blockIdx.x] = make_float2(ps, pc);
    }
}

__global__ __launch_bounds__(256) void ranknet_finalize_kernel(
    const float2* __restrict__ partials, int n, float* __restrict__ out)
{
    float s = 0.0f, c = 0.0f;
    for (int i = threadIdx.x; i < n; i += 256) {
        const float2 p = partials[i];
        s += p.x;
        c += p.y;
    }
    #pragma unroll
    for (int off = 32; off > 0; off >>= 1) {
        s += __shfl_xor(s, off);
        c += __shfl_xor(c, off);
    }
    __shared__ float2 wsum[4];
    const int wave = threadIdx.x >> 6;
    const int lane = threadIdx.x & 63;
    if (lane == 0) wsum[wave] = make_float2(s, c);
    __syncthreads();
    if (threadIdx.x == 0) {
        float ts = 0.0f, tc = 0.0f;
        #pragma unroll
        for (int w = 0; w < 4; ++w) { ts += wsum[w].x; tc += wsum[w].y; }
        out[0] = (tc > 0.0f) ? (ts / tc) : 0.0f;
    }
}

extern "C" void kernel_launch(void* const* d_in, const int* in_sizes, int n_in,
                              void* d_out, int out_size, void* d_ws, size_t ws_size,
                              hipStream_t stream) {
    const float4* scores4 = (const float4*)d_in[0];
    const int4*   rank4   = (const int4*)d_in[1];
    const int4*   mask4   = (const int4*)d_in[2];
    float*        out     = (float*)d_out;

    const int total   = in_sizes[0];        // B * 32 = 1,048,576
    const int nblocks = total / 1024;       // 1024 blocks, 32 batches each

    float2* partials = (float2*)d_ws;       // 1024 * 8B = 8 KB, every slot written

    ranknet_partial_kernel<<<nblocks, 256, 0, stream>>>(scores4, rank4, mask4, partials);
    ranknet_finalize_kernel<<<1, 256, 0, stream>>>(partials, nblocks, out);
}